// Round 7
// baseline (53.503 us; speedup 1.0000x reference)
//
#include <hip/hip_runtime.h>
#include <math.h>

#define BB 32
#define SS 2048
#define HH 1024
#define RR 64
#define H4 (HH/4)

// flag: 0 = int32, 1 = uint8(bool), 2 = float32
__device__ __forceinline__ bool read_mask(const void* m, int flag, int i) {
    if (flag == 1) return ((const unsigned char*)m)[i] != 0;
    if (flag == 2) return ((const float*)m)[i] != 0.0f;
    return ((const int*)m)[i] != 0;
}

__device__ __forceinline__ float dot4(float4 a, float4 b) {
    return a.x * b.x + a.y * b.y + a.z * b.z + a.w * b.w;
}

// ---- K1': rubric span pooling (bulk) + answer pool + matvec (overlapped) --
// grid = B*R = 2048, block = 256, blk = r*32 + b  (batch b's blocks -> XCD b%8).
// Every block pools its rubric span into u[idx] (already /len). Blocks with
// r < 16 additionally pool a[b] and compute v[b, r*64 .. r*64+64) — the old
// serial K1, now fully overlapped with the other 1536 blocks' span pooling.
// No intra-kernel handoff: u and v are consumed by K2' after the kernel
// boundary (end-of-dispatch release flushes L2, same mechanism R4/R6 already
// relied on for v). Block 0 zeroes the per-batch softmax counters.
__global__ void pool_all_k(const float4* __restrict__ seq,
                           const float4* __restrict__ W4,
                           const int* __restrict__ rspan,
                           const int* __restrict__ aspan,
                           const void* __restrict__ mask,
                           float4* __restrict__ u,
                           float* __restrict__ v,
                           unsigned int* __restrict__ cnt) {
    int blk = blockIdx.x, t = threadIdx.x;
    int b = blk & (BB - 1), r = blk >> 5;
    int idx = b * RR + r;
    int wave = t >> 6, lane = t & 63;

    // --- mask dtype classify (2048-B L2-resident scan; ~free) ---
    // uint8 bool => nonzero at i%4==1; f32 => nonzero only at i%4==3;
    // int32 => nonzero only at i%4==0.
    __shared__ int c1s, c3s;
    if (t == 0) { c1s = 0; c3s = 0; }
    __syncthreads();
    {
        const unsigned char* mb = (const unsigned char*)mask;
        int c1 = 0, c3 = 0;
        for (int i = t; i < BB * RR; i += 256) {
            if (mb[i]) {
                int p = i & 3;
                if (p == 1) c1 = 1;
                else if (p == 3) c3 = 1;
            }
        }
        if (c1) atomicOr(&c1s, 1);
        if (c3) atomicOr(&c3s, 1);
    }
    __syncthreads();
    int flag = c1s ? 1 : (c3s ? 2 : 0);
    bool mk = read_mask(mask, flag, idx);

    // --- rubric span mean pooling (thread t owns float4 chunk t of H) ---
    float4 acc = make_float4(0.f, 0.f, 0.f, 0.f);
    if (mk) {
        int s0 = rspan[2 * idx], s1 = rspan[2 * idx + 1];
        int len = s1 - s0; if (len < 1) len = 1;
        const float4* base = seq + (size_t)b * SS * H4 + t;
        for (int s = s0; s < s1; ++s) {
            float4 x = base[(size_t)s * H4];
            acc.x += x.x; acc.y += x.y; acc.z += x.z; acc.w += x.w;
        }
        float inv = 1.0f / (float)len;
        acc.x *= inv; acc.y *= inv; acc.z *= inv; acc.w *= inv;
    }
    u[(size_t)idx * 256 + t] = acc;     // coalesced 4 KB per rubric

    // --- producer duty: answer pool + matvec chunk (r < 16 only) ---
    if (r < 16) {
        int s0 = aspan[2 * b], s1 = aspan[2 * b + 1];
        int alen = s1 - s0; if (alen < 1) alen = 1;
        float4 a = make_float4(0.f, 0.f, 0.f, 0.f);
        const float4* base = seq + (size_t)b * SS * H4 + t;
        for (int s = s0; s < s1; ++s) {
            float4 x = base[(size_t)s * H4];
            a.x += x.x; a.y += x.y; a.z += x.z; a.w += x.w;
        }
        float inv = 1.0f / (float)alen;
        a.x *= inv; a.y *= inv; a.z *= inv; a.w *= inv;

        __shared__ float4 aS[256];
        aS[t] = a;
        __syncthreads();
        float4 al0 = aS[0 * 64 + lane];
        float4 al1 = aS[1 * 64 + lane];
        float4 al2 = aS[2 * 64 + lane];
        float4 al3 = aS[3 * 64 + lane];
        int hbase = r * 64 + wave * 16;
        for (int rr = 0; rr < 16; ++rr) {
            int h = hbase + rr;
            const float4* Wrow = W4 + (size_t)h * H4;
            float p = dot4(Wrow[0 * 64 + lane], al0)
                    + dot4(Wrow[1 * 64 + lane], al1)
                    + dot4(Wrow[2 * 64 + lane], al2)
                    + dot4(Wrow[3 * 64 + lane], al3);
            for (int off = 32; off; off >>= 1) p += __shfl_down(p, off);
            if (lane == 0) v[b * HH + h] = p;
        }
    }

    if (blk == 0 && t < BB) cnt[t] = 0u;   // re-zero softmax counters
}

// ---------------- K2': dot + fused softmax (featherweight) ----------------
// grid = B*R, block = 256. Reads u[idx] (4 KB) + v[b] (4 KB, L2/L3-hot),
// dots, block-reduces, then the R3-proven fence-free softmax handoff:
// relaxed agent-scope score store, s_waitcnt vmcnt(0), relaxed device-scope
// counter bump; 64th arriver runs the 64-wide softmax. No acquire/release.
__global__ void dot_softmax_k(const float4* __restrict__ u,
                              const float4* __restrict__ v4,
                              const void* __restrict__ mask,
                              const float* __restrict__ bias,
                              float* __restrict__ scores,
                              unsigned int* __restrict__ cnt,
                              float* __restrict__ out) {
    int blk = blockIdx.x, t = threadIdx.x;
    int b = blk & (BB - 1), r = blk >> 5;
    int idx = b * RR + r;
    int wave = t >> 6, lane = t & 63;

    __shared__ int c1s, c3s;
    if (t == 0) { c1s = 0; c3s = 0; }
    __syncthreads();
    {
        const unsigned char* mb = (const unsigned char*)mask;
        int c1 = 0, c3 = 0;
        for (int i = t; i < BB * RR; i += 256) {
            if (mb[i]) {
                int p = i & 3;
                if (p == 1) c1 = 1;
                else if (p == 3) c3 = 1;
            }
        }
        if (c1) atomicOr(&c1s, 1);
        if (c3) atomicOr(&c3s, 1);
    }
    __syncthreads();
    int flag = c1s ? 1 : (c3s ? 2 : 0);
    bool mk = read_mask(mask, flag, idx);

    float p = 0.f;
    if (mk) {
        float4 uu = u[(size_t)idx * 256 + t];
        float4 vv = v4[b * H4 + t];
        p = dot4(uu, vv);
    }
    __shared__ float red[4];
    __shared__ int lastB;
    for (int off = 32; off; off >>= 1) p += __shfl_down(p, off);
    if (lane == 0) red[wave] = p;
    __syncthreads();
    if (t == 0) {
        float s = red[0] + red[1] + red[2] + red[3];
        float val = mk ? (s + bias[0]) : -INFINITY;   // u already /len
        __hip_atomic_store(&scores[idx], val, __ATOMIC_RELAXED,
                           __HIP_MEMORY_SCOPE_AGENT);
        asm volatile("s_waitcnt vmcnt(0)" ::: "memory");  // score @ coherence pt
        unsigned old = atomicAdd(&cnt[b], 1u);            // relaxed, device
        asm volatile("" ::: "memory");
        lastB = (old == RR - 1);
    }
    __syncthreads();
    if (lastB && t < RR) {
        float x = __hip_atomic_load(&scores[b * RR + t], __ATOMIC_RELAXED,
                                    __HIP_MEMORY_SCOPE_AGENT);
        float m = x;
        for (int off = 32; off; off >>= 1) m = fmaxf(m, __shfl_xor(m, off));
        float e = expf(x - m);              // -inf lanes -> 0
        float s = e;
        for (int off = 32; off; off >>= 1) s += __shfl_xor(s, off);
        out[b * RR + t] = e / s;
    }
}

extern "C" void kernel_launch(void* const* d_in, const int* in_sizes, int n_in,
                              void* d_out, int out_size, void* d_ws, size_t ws_size,
                              hipStream_t stream) {
    const float* seq  = (const float*)d_in[0];
    const float* Wm   = (const float*)d_in[1];
    const float* bias = (const float*)d_in[2];
    const int*   rspan = (const int*)d_in[3];
    const int*   aspan = (const int*)d_in[4];
    const void*  mask  = d_in[5];

    char* ws = (char*)d_ws;
    unsigned int* cnt    = (unsigned int*)(ws + 256);       // 32 u32
    float*        scores = (float*)(ws + 4096);             // 2048 f
    float*        v      = (float*)(ws + 16384);            // 32*1024 f
    float*        u      = (float*)(ws + (1 << 20));        // 2048*1024 f = 8 MB

    pool_all_k<<<BB * RR, 256, 0, stream>>>(
        (const float4*)seq, (const float4*)Wm, rspan, aspan, mask,
        (float4*)u, v, cnt);
    dot_softmax_k<<<BB * RR, 256, 0, stream>>>(
        (const float4*)u, (const float4*)v, mask, bias,
        scores, cnt, (float*)d_out);
}